// Round 1
// baseline (3215.656 us; speedup 1.0000x reference)
//
#include <hip/hip_runtime.h>
#include <hip/hip_bf16.h>
#include <math.h>

#define B_ 8
#define N_ 8192
#define C_ 64
#define M_ 2048
#define K_ 32
#define OUT_ 128
#define CIN_ 67
#define HID_ 268
#define EPS_ 1e-6f

typedef short short8 __attribute__((ext_vector_type(8)));
typedef float floatx4 __attribute__((ext_vector_type(4)));

__device__ __forceinline__ unsigned short f2bf(float f) {
  unsigned u = __builtin_bit_cast(unsigned, f);
  u += 0x7fffu + ((u >> 16) & 1u);   // RNE (MFMA input casts only)
  return (unsigned short)(u >> 16);
}
__device__ __forceinline__ float bf2f(unsigned short h) {
  return __builtin_bit_cast(float, (unsigned)h << 16);
}

// Reference-matching distance (verified r13, bit-exact): square fused into the
// 3-element reduce as FMA, index-ascending.
__device__ __forceinline__ float d2fma(float ax, float ay, float az,
                                       float bx, float by, float bz) {
#pragma clang fp contract(off)
  float dx = ax - bx, dy = ay - by, dz = az - bz;
  return __builtin_fmaf(dz, dz, __builtin_fmaf(dy, dy, dx * dx));
}

__device__ __forceinline__ float gelu_tanh(float v) {
  const float k0 = 0.7978845608028654f;  // sqrt(2/pi)
  const float k1 = 0.044715f;
  float u = k0 * (v + k1 * v * v * v);
  return 0.5f * v * (1.0f + tanhf(u));
}

// Morton spread of a 4-bit value to bit positions 0,3,6,9
__device__ __forceinline__ int msp4(int v) {
  return (v & 1) | ((v & 2) << 2) | ((v & 4) << 4) | ((v & 8) << 6);
}

// ---------------- FPS v4: bound-pruned, one block per batch, 1024 threads --
// One-time Morton-cell counting sort gives each thread 8 spatially-coherent
// points. Per iteration: wave-level bbox bound (uniform skip), then lane-level
// group-bbox bound; only affected groups rerun the exact min-update. Skips
// are conservative (0.999 margin) so every retained d is bit-identical to the
// unpruned r13-verified chain: same d2fma, same fminf, u64 key max with
// first-global-index tie-break carried via ~idx (order-independent).
__global__ __launch_bounds__(1024) void fps_kernel(
    const float* __restrict__ x, const int* __restrict__ first_idx,
    float* __restrict__ centers) {   // = d_out[0 .. B*M*3), FLOAT32
  const int b = blockIdx.x;
  const int t = threadIdx.x;
  const int lane = t & 63;
  const int wv = t >> 6;             // wave 0..15
  const float* xb = x + (size_t)b * N_ * 3;

  __shared__ float s_xyz[N_ * 3];                  // 96 KB coord cache
  __shared__ int s_hist[4096];                     // 16 KB cell hist/cursor
  __shared__ unsigned short s_perm[N_];            // 16 KB sorted point ids
  __shared__ unsigned long long s_wkey[2][16];     // parity wave partials
  __shared__ int s_wsum[16];
  __shared__ float s_bb[16][6];

  // stage coords: 24576 floats = 6144 float4, coalesced, 6 per thread
  {
    const float4* src = (const float4*)xb;
    float4* dst = (float4*)s_xyz;
#pragma unroll
    for (int i = 0; i < 6; ++i) {
      int e = t + i * 1024;
      dst[e] = src[e];
    }
  }
  for (int i = t; i < 4096; i += 1024) s_hist[i] = 0;
  __syncthreads();

  // ---- batch bbox (any enclosing box is correct; used only for binning) ----
  float bx0 = INFINITY, bx1 = -INFINITY, by0 = INFINITY, by1 = -INFINITY,
        bz0 = INFINITY, bz1 = -INFINITY;
#pragma unroll
  for (int i = 0; i < 8; ++i) {
    int p = t + i * 1024;
    float X = s_xyz[p * 3 + 0], Y = s_xyz[p * 3 + 1], Z = s_xyz[p * 3 + 2];
    bx0 = fminf(bx0, X); bx1 = fmaxf(bx1, X);
    by0 = fminf(by0, Y); by1 = fmaxf(by1, Y);
    bz0 = fminf(bz0, Z); bz1 = fmaxf(bz1, Z);
  }
#pragma unroll
  for (int off = 1; off < 64; off <<= 1) {
    bx0 = fminf(bx0, __shfl_xor(bx0, off)); bx1 = fmaxf(bx1, __shfl_xor(bx1, off));
    by0 = fminf(by0, __shfl_xor(by0, off)); by1 = fmaxf(by1, __shfl_xor(by1, off));
    bz0 = fminf(bz0, __shfl_xor(bz0, off)); bz1 = fmaxf(bz1, __shfl_xor(bz1, off));
  }
  if (lane == 0) {
    s_bb[wv][0] = bx0; s_bb[wv][1] = bx1; s_bb[wv][2] = by0;
    s_bb[wv][3] = by1; s_bb[wv][4] = bz0; s_bb[wv][5] = bz1;
  }
  __syncthreads();
#pragma unroll
  for (int w = 0; w < 16; ++w) {
    bx0 = fminf(bx0, s_bb[w][0]); bx1 = fmaxf(bx1, s_bb[w][1]);
    by0 = fminf(by0, s_bb[w][2]); by1 = fmaxf(by1, s_bb[w][3]);
    bz0 = fminf(bz0, s_bb[w][4]); bz1 = fmaxf(bz1, s_bb[w][5]);
  }
  const float kS = 16.0f * (1.0f - 1e-6f);
  float rx = bx1 - bx0, ry = by1 - by0, rz = bz1 - bz0;
  float sxv = rx > 0.f ? kS / rx : 0.f;
  float syv = ry > 0.f ? kS / ry : 0.f;
  float szv = rz > 0.f ? kS / rz : 0.f;

  // ---- histogram (12-bit Morton cells) ----
#pragma unroll
  for (int i = 0; i < 8; ++i) {
    int p = t + i * 1024;
    int qx = (int)((s_xyz[p * 3 + 0] - bx0) * sxv);
    int qy = (int)((s_xyz[p * 3 + 1] - by0) * syv);
    int qz = (int)((s_xyz[p * 3 + 2] - bz0) * szv);
    qx = qx < 0 ? 0 : (qx > 15 ? 15 : qx);
    qy = qy < 0 ? 0 : (qy > 15 ? 15 : qy);
    qz = qz < 0 ? 0 : (qz > 15 ? 15 : qz);
    int c = msp4(qx) | (msp4(qy) << 1) | (msp4(qz) << 2);
    atomicAdd(&s_hist[c], 1);
  }
  __syncthreads();

  // ---- exclusive scan over 4096 bins (thread owns bins [4t,4t+4)) ----
  {
    int h0 = s_hist[t * 4 + 0], h1 = s_hist[t * 4 + 1];
    int h2 = s_hist[t * 4 + 2], h3 = s_hist[t * 4 + 3];
    int l1 = h0, l2 = h0 + h1, l3 = h0 + h1 + h2, tsum = l3 + h3;
    int incl = tsum;
#pragma unroll
    for (int off = 1; off < 64; off <<= 1) {
      int v = __shfl_up(incl, off);
      if (lane >= off) incl += v;
    }
    int texcl = incl - tsum;
    if (lane == 63) s_wsum[wv] = incl;
    __syncthreads();
    int woff = 0;
    for (int w = 0; w < 16; ++w) woff += (w < wv) ? s_wsum[w] : 0;
    int base0 = woff + texcl;
    s_hist[t * 4 + 0] = base0;
    s_hist[t * 4 + 1] = base0 + l1;
    s_hist[t * 4 + 2] = base0 + l2;
    s_hist[t * 4 + 3] = base0 + l3;
  }
  __syncthreads();

  // ---- scatter: s_perm[pos] = original point index ----
#pragma unroll
  for (int i = 0; i < 8; ++i) {
    int p = t + i * 1024;
    int qx = (int)((s_xyz[p * 3 + 0] - bx0) * sxv);
    int qy = (int)((s_xyz[p * 3 + 1] - by0) * syv);
    int qz = (int)((s_xyz[p * 3 + 2] - bz0) * szv);
    qx = qx < 0 ? 0 : (qx > 15 ? 15 : qx);
    qy = qy < 0 ? 0 : (qy > 15 ? 15 : qy);
    qz = qz < 0 ? 0 : (qz > 15 ? 15 : qz);
    int c = msp4(qx) | (msp4(qy) << 1) | (msp4(qz) << 2);
    int pos = atomicAdd(&s_hist[c], 1);
    s_perm[pos] = (unsigned short)p;
  }
  __syncthreads();

  // ---- load 8 sorted slots/thread; build group bbox ----
  float px[8], py[8], pz[8], d[8];
  unsigned lo[8];
  float gx0 = INFINITY, gx1 = -INFINITY, gy0 = INFINITY, gy1 = -INFINITY,
        gz0 = INFINITY, gz1 = -INFINITY;
#pragma unroll
  for (int i = 0; i < 8; ++i) {
    int p = (int)s_perm[t * 8 + i];
    px[i] = s_xyz[p * 3 + 0];
    py[i] = s_xyz[p * 3 + 1];
    pz[i] = s_xyz[p * 3 + 2];
    d[i] = INFINITY;   // fminf(inf, v) == v exactly -> first update installs d0
    lo[i] = 0xFFFFFFFFu - (unsigned)p;
    gx0 = fminf(gx0, px[i]); gx1 = fmaxf(gx1, px[i]);
    gy0 = fminf(gy0, py[i]); gy1 = fmaxf(gy1, py[i]);
    gz0 = fminf(gz0, pz[i]); gz1 = fmaxf(gz1, pz[i]);
  }
  // wave bbox (uniform across lanes after butterfly)
  float wx0 = gx0, wx1 = gx1, wy0 = gy0, wy1 = gy1, wz0 = gz0, wz1 = gz1;
#pragma unroll
  for (int off = 1; off < 64; off <<= 1) {
    wx0 = fminf(wx0, __shfl_xor(wx0, off)); wx1 = fmaxf(wx1, __shfl_xor(wx1, off));
    wy0 = fminf(wy0, __shfl_xor(wy0, off)); wy1 = fmaxf(wy1, __shfl_xor(wy1, off));
    wz0 = fminf(wz0, __shfl_xor(wz0, off)); wz1 = fmaxf(wz1, __shfl_xor(wz1, off));
  }

  int fi = first_idx[b];
  float ncx = s_xyz[fi * 3 + 0], ncy = s_xyz[fi * 3 + 1], ncz = s_xyz[fi * 3 + 2];
  if (t == 0) {
    size_t co = (size_t)b * M_ * 3;
    centers[co + 0] = ncx; centers[co + 1] = ncy; centers[co + 2] = ncz;
  }

  unsigned long long lk = 0x7F800000ULL << 32;  // cached lane key (gmax = +inf)
  unsigned long long wk = lk;                   // cached wave partial key

  for (int it = 1; it < M_; ++it) {
    // wave-level conservative bound (uniform branch)
    float wdx = fmaxf(fmaxf(wx0 - ncx, ncx - wx1), 0.f);
    float wdy = fmaxf(fmaxf(wy0 - ncy, ncy - wy1), 0.f);
    float wdz = fmaxf(fmaxf(wz0 - ncz, ncz - wz1), 0.f);
    float wlb = __builtin_fmaf(wdz, wdz, __builtin_fmaf(wdy, wdy, wdx * wdx));
    float wgm = __builtin_bit_cast(float, (unsigned)(wk >> 32));
    if (wlb * 0.999f < wgm) {
      // lane-level group bound
      float gdx = fmaxf(fmaxf(gx0 - ncx, ncx - gx1), 0.f);
      float gdy = fmaxf(fmaxf(gy0 - ncy, ncy - gy1), 0.f);
      float gdz = fmaxf(fmaxf(gz0 - ncz, ncz - gz1), 0.f);
      float glb = __builtin_fmaf(gdz, gdz, __builtin_fmaf(gdy, gdy, gdx * gdx));
      float ggm = __builtin_bit_cast(float, (unsigned)(lk >> 32));
      if (glb * 0.999f < ggm) {
        unsigned long long k[8];
#pragma unroll
        for (int i = 0; i < 8; ++i) {
          float dd = d2fma(px[i], py[i], pz[i], ncx, ncy, ncz);
          float dm = fminf(d[i], dd);
          d[i] = dm;
          k[i] = ((unsigned long long)__builtin_bit_cast(unsigned, dm) << 32) |
                 (unsigned long long)lo[i];
        }
#pragma unroll
        for (int s = 4; s >= 1; s >>= 1)
#pragma unroll
          for (int i = 0; i < s; ++i)
            k[i] = k[i] > k[i + s] ? k[i] : k[i + s];
        lk = k[0];
      }
      // wave reduce (64 lanes) -> new cached wave partial
      unsigned long long kk = lk;
#pragma unroll
      for (int off = 1; off < 64; off <<= 1) {
        unsigned long long o = __shfl_xor(kk, off);
        kk = kk > o ? kk : o;
      }
      wk = kk;
    }
    if (lane == 0) s_wkey[it & 1][wv] = wk;
    __syncthreads();
    // cross-wave reduce: lane reads entry lane&15, 4-step butterfly
    unsigned long long gk = s_wkey[it & 1][lane & 15];
#pragma unroll
    for (int off = 1; off < 16; off <<= 1) {
      unsigned long long o = __shfl_xor(gk, off);
      gk = gk > o ? gk : o;
    }
    int gi = (int)(0xFFFFFFFFu - (unsigned)(gk & 0xFFFFFFFFull));
    int gs = __builtin_amdgcn_readfirstlane(gi);   // uniform index
    ncx = s_xyz[gs * 3 + 0];                        // LDS broadcast fetch
    ncy = s_xyz[gs * 3 + 1];
    ncz = s_xyz[gs * 3 + 2];
    if (t == 0) {
      size_t co = ((size_t)b * M_ + it) * 3;
      centers[co + 0] = ncx; centers[co + 1] = ncy; centers[co + 2] = ncz;
    }
    // no second barrier: next iteration writes the other parity buffer
  }
}

// ---------------- Ball query: one wave per center -------------------------
#define CAP_ 512
__global__ __launch_bounds__(256) void ballq_kernel(
    const float* __restrict__ x, const float* __restrict__ centers,
    int* __restrict__ nbr) {
  __shared__ float cd[4][CAP_];
  __shared__ int cidx[4][CAP_];
  const int w = threadIdx.x >> 6;
  const int lane = threadIdx.x & 63;
  const int cm = blockIdx.x * 4 + w;
  const int b = cm >> 11;  // / M_
  const float* xb = x + (size_t)b * N_ * 3;
  const float ccx = centers[(size_t)cm * 3 + 0];
  const float ccy = centers[(size_t)cm * 3 + 1];
  const float ccz = centers[(size_t)cm * 3 + 2];
  int count = 0;
  for (int base = 0; base < N_; base += 64) {
    int p = base + lane;
    float d2 = d2fma(xb[p * 3 + 0], xb[p * 3 + 1], xb[p * 3 + 2], ccx, ccy, ccz);
    bool isin = d2 < 0.09f;   // f32(0.3**2), strict <
    unsigned long long m = __ballot(isin);
    if (isin) {
      int pos = count + (int)__popcll(m & ((1ull << lane) - 1ull));
      if (pos < CAP_) { cd[w][pos] = d2; cidx[w][pos] = p; }  // index-ordered = stable
    }
    count += (int)__popcll(m);
  }
  if (count > CAP_) count = CAP_;
  int nw = count < K_ ? count : K_;
  for (int cc = lane; cc < count; cc += 64) {
    float dcc = cd[w][cc];
    int rank = 0;
    for (int j = 0; j < count; ++j) {
      float dj = cd[w][j];
      rank += (dj < dcc || (dj == dcc && j < cc)) ? 1 : 0;  // stable order
    }
    if (rank < K_) nbr[(size_t)cm * K_ + rank] = cidx[w][cc];
  }
  // pad: reference's -1 wraps to N-1 on gather
  for (int s = nw + lane; s < K_; s += 64) nbr[(size_t)cm * K_ + s] = N_ - 1;
}

// ---------------- Pack f32 weights into MFMA B-fragment order (bf16) ------
// B-frag for 16x16x32: lane holds B[k = (lane>>4)*8 + j][n = lane&15].
__global__ __launch_bounds__(256) void pack_kernel(
    const float* __restrict__ w1, const float* __restrict__ w2,
    unsigned short* __restrict__ w1p, unsigned short* __restrict__ w2p) {
  int e = blockIdx.x * 256 + threadIdx.x;
  if (e < 3 * 17 * 64 * 8) {
    int j = e & 7, lane = (e >> 3) & 63, fi = e >> 9;
    int kt = fi / 17, nt = fi - kt * 17;
    int k = kt * 32 + (lane >> 4) * 8 + j;
    int n = nt * 16 + (lane & 15);
    float v = (k < CIN_ && n < HID_) ? w1[k * HID_ + n] : 0.f;
    w1p[e] = f2bf(v);
  } else {
    int e2 = e - 3 * 17 * 64 * 8;
    if (e2 < 9 * 8 * 64 * 8) {
      int j = e2 & 7, lane = (e2 >> 3) & 63, fi = e2 >> 9;
      int kt = fi >> 3, nt = fi & 7;
      int k = kt * 32 + (lane >> 4) * 8 + j;
      int n = nt * 16 + (lane & 15);
      float v = (k < HID_) ? w2[k * OUT_ + n] : 0.f;
      w2p[e2] = f2bf(v);
    }
  }
}

// ---------------- Fused gather + MLP + LN + max, one center at a time -----
__global__ __launch_bounds__(512) void mlp_kernel(
    const float* __restrict__ x, const float* __restrict__ features,
    const float* __restrict__ centers, const int* __restrict__ nbr,
    const unsigned short* __restrict__ w1p, const float* __restrict__ b1,
    const float* __restrict__ g1, const float* __restrict__ be1,
    const unsigned short* __restrict__ w2p, const float* __restrict__ b2,
    const float* __restrict__ g2, const float* __restrict__ be2,
    float* __restrict__ out1) {
  __shared__ __align__(16) unsigned short A1[32 * 104];  // comb bf16, K1pad=96 (+8 pad)
  __shared__ __align__(16) unsigned short H1[32 * 296];  // h1 bf16, K2pad=288 (+8 pad)
  __shared__ float H2[32 * 132];                          // h2 f32 (pre-LN2), +4 pad
  __shared__ float s_sum[32], s_sum2[32], s_mu[32], s_rs[32];
  __shared__ int s_nbr[32];
  __shared__ float s_ctr[3];

  const int tid = threadIdx.x;
  const int lane = tid & 63;
  const int wv = tid >> 6;   // wave 0..7
  const int q4 = lane >> 4;  // quad 0..3
  const int nl = lane & 15;

  for (int e = tid; e < 32 * 104; e += 512) A1[e] = 0;
  for (int e = tid; e < 32 * 296; e += 512) H1[e] = 0;
  __syncthreads();

  for (int cm = blockIdx.x; cm < B_ * M_; cm += gridDim.x) {
    const int b = cm >> 11;
    if (tid < 32) s_nbr[tid] = nbr[(size_t)cm * K_ + tid];
    else if (tid < 64) s_sum[tid - 32] = 0.f;
    else if (tid < 96) s_sum2[tid - 64] = 0.f;
    else if (tid < 99) s_ctr[tid - 96] = centers[(size_t)cm * 3 + (tid - 96)];
    __syncthreads();

    // gather: 16 threads per neighbor row
    {
      int r = tid >> 4, j = tid & 15;
      int idx = s_nbr[r];
      const float4* frow = (const float4*)(features + ((size_t)b * N_ + idx) * C_);
      float4 f4 = frow[j];
      int base = r * 104 + j * 4;
      A1[base + 0] = f2bf(f4.x); A1[base + 1] = f2bf(f4.y);
      A1[base + 2] = f2bf(f4.z); A1[base + 3] = f2bf(f4.w);
      if (j == 0) {
        const float* xp = x + ((size_t)b * N_ + idx) * 3;
        A1[r * 104 + 64] = f2bf(xp[0] - s_ctr[0]);
        A1[r * 104 + 65] = f2bf(xp[1] - s_ctr[1]);
        A1[r * 104 + 66] = f2bf(xp[2] - s_ctr[2]);
      }
    }
    __syncthreads();

    // GEMM1: (32x96) @ (96x272), B-frags register-cached from global
    for (int nt = wv; nt < 17; nt += 8) {
      short8 bfr[3];
#pragma unroll
      for (int kt = 0; kt < 3; ++kt)
        bfr[kt] = *(const short8*)(w1p + (size_t)((kt * 17 + nt) * 64 + lane) * 8);
      int col = nt * 16 + nl;
      bool cok = col < HID_;
      float bias = cok ? b1[col] : 0.f;
#pragma unroll
      for (int mt = 0; mt < 2; ++mt) {
        floatx4 acc = {0.f, 0.f, 0.f, 0.f};
        const unsigned short* ap = A1 + (mt * 16 + nl) * 104 + q4 * 8;
#pragma unroll
        for (int kt = 0; kt < 3; ++kt) {
          short8 a = *(const short8*)(ap + kt * 32);
          acc = __builtin_amdgcn_mfma_f32_16x16x32_bf16(a, bfr[kt], acc, 0, 0, 0);
        }
#pragma unroll
        for (int r = 0; r < 4; ++r) {
          int row = mt * 16 + q4 * 4 + r;
          float g = 0.f;
          if (cok) {
            float v = acc[r] + bias;
            g = gelu_tanh(v);
            H1[row * 296 + col] = f2bf(g);
          }
          float s1 = g, s2 = g * g;
#pragma unroll
          for (int off = 1; off < 16; off <<= 1) {
            s1 += __shfl_xor(s1, off);
            s2 += __shfl_xor(s2, off);
          }
          if (nl == 0) { atomicAdd(&s_sum[row], s1); atomicAdd(&s_sum2[row], s2); }
        }
      }
    }
    __syncthreads();
    if (tid < 32) {
      float mu = s_sum[tid] * (1.f / HID_);
      float var = s_sum2[tid] * (1.f / HID_) - mu * mu;
      s_mu[tid] = mu;
      s_rs[tid] = rsqrtf(var + EPS_);
    }
    __syncthreads();
    // LN1 in place (bf16), zero stats for LN2
    for (int e = tid; e < K_ * HID_; e += 512) {
      int r = e / HID_, c = e - r * HID_;
      float g = bf2f(H1[r * 296 + c]);
      float v = (g - s_mu[r]) * s_rs[r] * g1[c] + be1[c];
      H1[r * 296 + c] = f2bf(v);
    }
    if (tid < 32) { s_sum[tid] = 0.f; s_sum2[tid] = 0.f; }
    __syncthreads();

    // GEMM2: (32x288) @ (288x128), one n-tile per wave
    {
      int nt = wv;
      short8 bfr2[9];
#pragma unroll
      for (int kt = 0; kt < 9; ++kt)
        bfr2[kt] = *(const short8*)(w2p + (size_t)((kt * 8 + nt) * 64 + lane) * 8);
      int col = nt * 16 + nl;
      float bias = b2[col];
#pragma unroll
      for (int mt = 0; mt < 2; ++mt) {
        floatx4 acc = {0.f, 0.f, 0.f, 0.f};
        const unsigned short* ap = H1 + (mt * 16 + nl) * 296 + q4 * 8;
#pragma unroll
        for (int kt = 0; kt < 9; ++kt) {
          short8 a = *(const short8*)(ap + kt * 32);
          acc = __builtin_amdgcn_mfma_f32_16x16x32_bf16(a, bfr2[kt], acc, 0, 0, 0);
        }
#pragma unroll
        for (int r = 0; r < 4; ++r) {
          int row = mt * 16 + q4 * 4 + r;
          float v = acc[r] + bias;
          H2[row * 132 + col] = v;
          float s1 = v, s2 = v * v;
#pragma unroll
          for (int off = 1; off < 16; off <<= 1) {
            s1 += __shfl_xor(s1, off);
            s2 += __shfl_xor(s2, off);
          }
          if (nl == 0) { atomicAdd(&s_sum[row], s1); atomicAdd(&s_sum2[row], s2); }
        }
      }
    }
    __syncthreads();
    if (tid < 32) {
      float mu = s_sum[tid] * (1.f / OUT_);
      float var = s_sum2[tid] * (1.f / OUT_) - mu * mu;
      s_mu[tid] = mu;
      s_rs[tid] = rsqrtf(var + EPS_);
    }
    __syncthreads();
    if (tid < OUT_) {
      int col = tid;
      float gg = g2[col], bb = be2[col];
      float mx = -3.4e38f;
#pragma unroll 4
      for (int r = 0; r < K_; ++r) {
        float v = H2[r * 132 + col];
        float o = (v - s_mu[r]) * s_rs[r] * gg + bb;
        mx = fmaxf(mx, o);
      }
      out1[(size_t)cm * OUT_ + col] = mx;   // FLOAT32 output
    }
    __syncthreads();
  }
}

extern "C" void kernel_launch(void* const* d_in, const int* in_sizes, int n_in,
                              void* d_out, int out_size, void* d_ws, size_t ws_size,
                              hipStream_t stream) {
  const float* x = (const float*)d_in[0];
  const float* features = (const float*)d_in[1];
  const int* first_idx = (const int*)d_in[2];
  const float* w1 = (const float*)d_in[3];
  const float* b1 = (const float*)d_in[4];
  const float* g1 = (const float*)d_in[5];
  const float* be1 = (const float*)d_in[6];
  const float* w2 = (const float*)d_in[7];
  const float* b2 = (const float*)d_in[8];
  const float* g2 = (const float*)d_in[9];
  const float* be2 = (const float*)d_in[10];

  // d_out is FLOAT32: centers (8,2048,3) then out (8,2048,128), concatenated.
  float* centers = (float*)d_out;
  float* out1 = (float*)d_out + (size_t)B_ * M_ * 3;

  // ws layout (bytes): nbr [0,2097152) | w1p [2097152,2149376) | w2p [2149376,2223104)
  int* nbr = (int*)d_ws;
  unsigned short* w1p = (unsigned short*)((char*)d_ws + 2097152);
  unsigned short* w2p = (unsigned short*)((char*)d_ws + 2149376);

  pack_kernel<<<dim3(246), dim3(256), 0, stream>>>(w1, w2, w1p, w2p);
  fps_kernel<<<dim3(B_), dim3(1024), 0, stream>>>(x, first_idx, centers);
  ballq_kernel<<<dim3((B_ * M_) / 4), dim3(256), 0, stream>>>(x, centers, nbr);
  mlp_kernel<<<dim3(512), dim3(512), 0, stream>>>(x, features, centers, nbr,
                                                  w1p, b1, g1, be1, w2p, b2, g2, be2, out1);
}